// Round 5
// baseline (2583.330 us; speedup 1.0000x reference)
//
#include <hip/hip_runtime.h>
#include <cstdint>

#define HDIM 128
#define BN_EPS_F 1e-5f
#define BSHIFT 6  // 64 nodes per bucket

typedef _Float16 half8 __attribute__((ext_vector_type(8)));
typedef _Float16 half2v __attribute__((ext_vector_type(2)));
typedef float f32x4 __attribute__((ext_vector_type(4)));

#define PA 136  // f16 pitch of A/H tiles
#define PW 72   // f16 pitch of W slabs

// ============================ Bucketed CSR build ============================
// bucket = dst >> 6 (64 nodes each). 3 passes: bucket-hist, pair-scatter into
// bucket-ordered array, per-bucket exact build (LDS counters, L2-local writes).

__global__ __launch_bounds__(256) void bucket_hist(const int* __restrict__ dst, int E,
                                                   int* __restrict__ bcnt, int NBUK) {
  __shared__ int lcnt[2048];
  int tid = threadIdx.x;
  for (int k = tid; k < 2048; k += 256) lcnt[k] = 0;
  __syncthreads();
  int i = blockIdx.x * blockDim.x + tid;
  int stride = gridDim.x * blockDim.x;
  for (; i < E; i += stride) atomicAdd(&lcnt[dst[i] >> BSHIFT], 1);
  __syncthreads();
  for (int k = tid; k < NBUK; k += 256) {
    int v = lcnt[k];
    if (v) atomicAdd(&bcnt[k], v);
  }
}

__global__ __launch_bounds__(1024) void bucket_scan(const int* __restrict__ bcnt,
    int* __restrict__ bbase, int* __restrict__ bcur, int NBUK, int E) {
  __shared__ int sd[1024];
  int t = threadIdx.x;
  int c0 = (2 * t < NBUK) ? bcnt[2 * t] : 0;
  int c1 = (2 * t + 1 < NBUK) ? bcnt[2 * t + 1] : 0;
  sd[t] = c0 + c1;
  __syncthreads();
  for (int o = 1; o < 1024; o <<= 1) {
    int v = (t >= o) ? sd[t - o] : 0;
    __syncthreads();
    sd[t] += v;
    __syncthreads();
  }
  int excl = sd[t] - (c0 + c1);
  if (2 * t < NBUK) { bbase[2 * t] = excl; bcur[2 * t] = excl; }
  if (2 * t + 1 < NBUK) { bbase[2 * t + 1] = excl + c0; bcur[2 * t + 1] = excl + c0; }
  if (t == 0) bbase[NBUK] = E;
}

__global__ __launch_bounds__(256) void bucket_scatter(const int* __restrict__ src,
    const int* __restrict__ dst, int E, int* __restrict__ bcur, int2* __restrict__ pairs) {
  int i = blockIdx.x * blockDim.x + threadIdx.x;
  int stride = gridDim.x * blockDim.x;
  for (; i < E; i += stride) {
    int d = dst[i];
    int p = atomicAdd(&bcur[d >> BSHIFT], 1);
    pairs[p] = make_int2(src[i], d);
  }
}

__global__ __launch_bounds__(256) void csr_build(const int2* __restrict__ pairs,
    const int* __restrict__ bbase, int* __restrict__ rowptr, int* __restrict__ col,
    int N, int NBUK) {
  __shared__ int cnt[64];
  __shared__ int off[65];
  int b = blockIdx.x, tid = threadIdx.x;
  int s = bbase[b], e = bbase[b + 1];
  if (tid < 64) cnt[tid] = 0;
  __syncthreads();
  for (int i = s + tid; i < e; i += 256) atomicAdd(&cnt[pairs[i].y & 63], 1);
  __syncthreads();
  if (tid == 0) {
    int r = 0;
    for (int k = 0; k < 64; ++k) { off[k] = r; r += cnt[k]; }
    off[64] = r;
  }
  __syncthreads();
  int node0 = b << BSHIFT;
  if (tid < 64) {
    int node = node0 + tid;
    if (node < N) rowptr[node] = s + off[tid];
    cnt[tid] = off[tid];  // reuse as cursor
  }
  __syncthreads();
  for (int i = s + tid; i < e; i += 256) {
    int2 p = pairs[i];
    int pos = atomicAdd(&cnt[p.y & 63], 1);
    col[s + pos] = p.x;
  }
  if (b == 0 && tid == 0) rowptr[N] = bbase[NBUK];
}

// ============================ Weight prep (one kernel) ============================
// All weights -> transposed [n][k] f16 hi/lo. Layout: head_w1 @0 (32768),
// head_w2 @32768 (32768), unit u: w1 @65536+u*32768, w2 @+16384.
__global__ __launch_bounds__(256) void wprep_all(const float* __restrict__ hw1,
    const float* __restrict__ hw2, const float* __restrict__ rw1, const float* __restrict__ rw2,
    _Float16* __restrict__ hi, _Float16* __restrict__ lo) {
  int gid = blockIdx.x * 256 + threadIdx.x;
  if (gid >= 262144) return;
  const float* W;
  int K, Nn, off;
  if (gid < 32768) { W = hw1; K = 128; Nn = 256; off = 0; }
  else if (gid < 65536) { W = hw2; K = 256; Nn = 128; off = 32768; }
  else {
    int j = (gid - 65536) >> 14;
    int u = j >> 1;
    W = (j & 1) ? rw2 + (size_t)u * 16384 : rw1 + (size_t)u * 16384;
    K = 128; Nn = 128; off = 65536 + j * 16384;
  }
  int idx = gid - off;
  int n = idx / K, k = idx - n * K;
  float v = W[(size_t)k * Nn + n];
  _Float16 h = (_Float16)v;
  hi[gid] = h;
  lo[gid] = (_Float16)(v - (float)h);
}

// ============================ Fused unit: gather(+BN+ReLU) -> MFMA MLP ============
__device__ __forceinline__ void stage_w_slab(_Float16* dsth, _Float16* dstl,
    const _Float16* __restrict__ gh, const _Float16* __restrict__ gl, int stride, int koff) {
  int tid = threadIdx.x;
#pragma unroll
  for (int it = 0; it < 4; ++it) {
    int l = tid + it * 256;
    int r = l >> 3, ch = (l & 7) * 8;
    *(half8*)&dsth[r * PW + ch] = *(const half8*)&gh[(size_t)r * stride + koff + ch];
    *(half8*)&dstl[r * PW + ch] = *(const half8*)&gl[(size_t)r * stride + koff + ch];
  }
}

template <int MF>
__device__ __forceinline__ void gemm_slab(const _Float16* Sh, const _Float16* Sl,
    const _Float16* Wh, const _Float16* Wl, int rowbase, int l15, int l4, int wc, int slab,
    f32x4 (&acc)[MF][4]) {
#pragma unroll
  for (int split = 0; split < 3; ++split) {
    const _Float16* as = (split == 1) ? Sl : Sh;
    const _Float16* bs = (split == 2) ? Wl : Wh;
#pragma unroll
    for (int kf = 0; kf < 2; ++kf) {
      int ka = slab * 64 + kf * 32 + l4 * 8;
      int kw = kf * 32 + l4 * 8;
      half8 a[MF], b[4];
#pragma unroll
      for (int m = 0; m < MF; ++m)
        a[m] = *(const half8*)&as[(rowbase + m * 16 + l15) * PA + ka];
#pragma unroll
      for (int f = 0; f < 4; ++f)
        b[f] = *(const half8*)&bs[(wc * 64 + f * 16 + l15) * PW + kw];
#pragma unroll
      for (int m = 0; m < MF; ++m)
#pragma unroll
        for (int f = 0; f < 4; ++f)
          acc[m][f] = __builtin_amdgcn_mfma_f32_16x16x32_f16(a[m], b[f], acc[m][f], 0, 0, 0);
    }
  }
}

// BNT=1: gather transform y = relu(a*h+b) derived from producer raw stats.
template <int MF, int NH, int BNT>
__global__ __launch_bounds__(256, 2) void fused_unit_kernel(
    const float* __restrict__ In, float* __restrict__ Out,
    const int* __restrict__ rowptr, const int* __restrict__ col,
    const float* __restrict__ pstats, const float* __restrict__ pg,
    const float* __restrict__ pbeta, float invN,
    const _Float16* __restrict__ w1hi, const _Float16* __restrict__ w1lo,
    const float* __restrict__ b1,
    const _Float16* __restrict__ w2hi, const _Float16* __restrict__ w2lo,
    const float* __restrict__ b2, float* __restrict__ stats, int N) {
  constexpr int BM = MF * 32;
  __shared__ _Float16 Ab[2][BM * PA];
  __shared__ _Float16 Wb[2][128 * PW];
  __shared__ _Float16 Hb[NH == 2 ? 2 : 1][NH == 2 ? BM * PA : 1];

  const int tid = threadIdx.x;
  const int wave = tid >> 6, lane = tid & 63;
  const int wr = wave >> 1, wc = wave & 1;
  const int l15 = lane & 15, l4 = lane >> 4;
  const int row0 = blockIdx.x * BM;
  const int rowbase = wr * (MF * 16);

  // per-lane BN coeffs for cols {2*lane, 2*lane+1}
  float a0 = 1.f, a1 = 1.f, bb0 = 0.f, bb1 = 0.f;
  if constexpr (BNT) {
    int c0 = 2 * lane, c1 = 2 * lane + 1;
    float m0 = pstats[c0] * invN, m1 = pstats[c1] * invN;
    float v0 = fmaxf(pstats[128 + c0] * invN - m0 * m0, 0.f);
    float v1 = fmaxf(pstats[128 + c1] * invN - m1 * m1, 0.f);
    a0 = pg[c0] * rsqrtf(v0 + BN_EPS_F);
    a1 = pg[c1] * rsqrtf(v1 + BN_EPS_F);
    bb0 = pbeta[c0] - m0 * a0;
    bb1 = pbeta[c1] - m1 * a1;
  }

  // ---- gather + aggregate + hi/lo split straight into LDS ----
  const float2* Xv = (const float2*)In;
  for (int rr = wave; rr < BM; rr += 4) {
    int node = row0 + rr;
    float2 acc = make_float2(0.f, 0.f);
    if (node < N) {
      float2 v = Xv[(size_t)node * 64 + lane];  // self term
      if constexpr (BNT) {
        v.x = fmaxf(fmaf(v.x, a0, bb0), 0.f);
        v.y = fmaxf(fmaf(v.y, a1, bb1), 0.f);
      }
      acc = v;
      int s = rowptr[node], e = rowptr[node + 1];
      int i = s;
      for (; i + 8 <= e; i += 8) {
        float2 t[8];
#pragma unroll
        for (int u = 0; u < 8; ++u) t[u] = Xv[(size_t)col[i + u] * 64 + lane];
#pragma unroll
        for (int u = 0; u < 8; ++u) {
          float2 w = t[u];
          if constexpr (BNT) {
            w.x = fmaxf(fmaf(w.x, a0, bb0), 0.f);
            w.y = fmaxf(fmaf(w.y, a1, bb1), 0.f);
          }
          acc.x += w.x; acc.y += w.y;
        }
      }
      for (; i < e; ++i) {
        float2 w = Xv[(size_t)col[i] * 64 + lane];
        if constexpr (BNT) {
          w.x = fmaxf(fmaf(w.x, a0, bb0), 0.f);
          w.y = fmaxf(fmaf(w.y, a1, bb1), 0.f);
        }
        acc.x += w.x; acc.y += w.y;
      }
    }
    _Float16 hx = (_Float16)acc.x, hy = (_Float16)acc.y;
    half2v hh = {hx, hy};
    half2v ll = {(_Float16)(acc.x - (float)hx), (_Float16)(acc.y - (float)hy)};
    *(half2v*)&Ab[0][rr * PA + 2 * lane] = hh;
    *(half2v*)&Ab[1][rr * PA + 2 * lane] = ll;
  }

  _Float16 *Hh, *Hl;
  if constexpr (NH == 2) { Hh = Hb[0]; Hl = Hb[1]; }
  else { Hh = Ab[0]; Hl = Ab[1]; }

  f32x4 acc2[MF][4];
#pragma unroll
  for (int f = 0; f < 4; ++f) {
    float bv = b2[wc * 64 + f * 16 + l15];
#pragma unroll
    for (int m = 0; m < MF; ++m) acc2[m][f] = (f32x4){bv, bv, bv, bv};
  }

  for (int h = 0; h < NH; ++h) {
    f32x4 acc1[MF][4];
#pragma unroll
    for (int f = 0; f < 4; ++f) {
      float bv = b1[h * 128 + wc * 64 + f * 16 + l15];
#pragma unroll
      for (int m = 0; m < MF; ++m) acc1[m][f] = (f32x4){bv, bv, bv, bv};
    }
#pragma unroll
    for (int slab = 0; slab < 2; ++slab) {
      __syncthreads();  // gather done / prior W readers done
      stage_w_slab(Wb[0], Wb[1], w1hi + (size_t)h * 128 * 128, w1lo + (size_t)h * 128 * 128,
                   128, slab * 64);
      __syncthreads();
      gemm_slab<MF>(Ab[0], Ab[1], Wb[0], Wb[1], rowbase, l15, l4, wc, slab, acc1);
    }
    __syncthreads();  // all A/W reads done (alias safety for NH==1)
    // ReLU + hi/lo split -> H  (C/D: row=(lane>>4)*4+reg, col=lane&15)
#pragma unroll
    for (int m = 0; m < MF; ++m)
#pragma unroll
      for (int f = 0; f < 4; ++f)
#pragma unroll
        for (int r = 0; r < 4; ++r) {
          float v = fmaxf(acc1[m][f][r], 0.f);
          _Float16 hh = (_Float16)v;
          int row = rowbase + m * 16 + l4 * 4 + r;
          int ck = wc * 64 + f * 16 + l15;
          Hh[row * PA + ck] = hh;
          Hl[row * PA + ck] = (_Float16)(v - (float)hh);
        }
#pragma unroll
    for (int slab = 0; slab < 2; ++slab) {
      __syncthreads();
      stage_w_slab(Wb[0], Wb[1], w2hi, w2lo, NH * 128, h * 128 + slab * 64);
      __syncthreads();
      gemm_slab<MF>(Hh, Hl, Wb[0], Wb[1], rowbase, l15, l4, wc, slab, acc2);
    }
  }

  // ---- epilogue: store + BN raw-stat partials ----
  __syncthreads();
  float* psum = (float*)&Wb[0][0];
  float* psq = psum + 256;
#pragma unroll
  for (int f = 0; f < 4; ++f) {
    float s = 0.f, q = 0.f;
#pragma unroll
    for (int m = 0; m < MF; ++m)
#pragma unroll
      for (int r = 0; r < 4; ++r) {
        int grow = row0 + rowbase + m * 16 + l4 * 4 + r;
        float v = acc2[m][f][r];
        if (grow < N) {
          Out[(size_t)grow * HDIM + wc * 64 + f * 16 + l15] = v;
          s += v;
          q += v * v;
        }
      }
    s += __shfl_xor(s, 16); q += __shfl_xor(q, 16);
    s += __shfl_xor(s, 32); q += __shfl_xor(q, 32);
    if (l4 == 0) {
      psum[wr * 128 + wc * 64 + f * 16 + l15] = s;
      psq[wr * 128 + wc * 64 + f * 16 + l15] = q;
    }
  }
  __syncthreads();
  if (tid < 128) {
    atomicAdd(&stats[tid], psum[tid] + psum[128 + tid]);
    atomicAdd(&stats[128 + tid], psq[tid] + psq[128 + tid]);
  }
}

// ============================ BN apply (+identity), materializing ============================
__global__ __launch_bounds__(256) void bn_relu_kernel(float* __restrict__ out,
    const float* __restrict__ in, const float* __restrict__ stats, const float* __restrict__ g,
    const float* __restrict__ beta, float invN, const float* __restrict__ identity, int nvec) {
  __shared__ float ab[256];
  int tid = threadIdx.x;
  if (tid < 128) {
    float m = stats[tid] * invN;
    float v = fmaxf(stats[128 + tid] * invN - m * m, 0.f);
    float a = g[tid] * rsqrtf(v + BN_EPS_F);
    ab[tid] = a;
    ab[128 + tid] = beta[tid] - m * a;
  }
  __syncthreads();
  int i = blockIdx.x * blockDim.x + tid;
  int stride = gridDim.x * blockDim.x;
  for (; i < nvec; i += stride) {
    int c4 = (i & 31) * 4;
    float4 x = ((const float4*)in)[i];
    float4 a = *(const float4*)&ab[c4];
    float4 b = *(const float4*)&ab[128 + c4];
    float4 o;
    o.x = fmaxf(fmaf(x.x, a.x, b.x), 0.f);
    o.y = fmaxf(fmaf(x.y, a.y, b.y), 0.f);
    o.z = fmaxf(fmaf(x.z, a.z, b.z), 0.f);
    o.w = fmaxf(fmaf(x.w, a.w, b.w), 0.f);
    if (identity) {
      float4 id = ((const float4*)identity)[i];
      o.x += id.x; o.y += id.y; o.z += id.z; o.w += id.w;
    }
    ((float4*)out)[i] = o;
  }
}

// ============================ Tail: gather + GIN(128->32->3) ============================
__global__ __launch_bounds__(256, 2) void tail_fused_kernel(
    const float* __restrict__ In, const int* __restrict__ rowptr, const int* __restrict__ col,
    const float* __restrict__ W1, const float* __restrict__ b1,
    const float* __restrict__ W2, const float* __restrict__ b2,
    float* __restrict__ out, int N) {
  __shared__ float Xs[64][132];
  __shared__ float W1s[128][32];
  __shared__ float H1s[64][36];
  __shared__ float W2s[96];
  __shared__ float b1s[32];
  __shared__ float b2s[3];
  int tid = threadIdx.x;
  int wave = tid >> 6, lane = tid & 63;
  int row0 = blockIdx.x * 64;
  const float2* Xv = (const float2*)In;
  for (int rr = wave; rr < 64; rr += 4) {
    int node = row0 + rr;
    float2 acc = make_float2(0.f, 0.f);
    if (node < N) {
      acc = Xv[(size_t)node * 64 + lane];
      int s = rowptr[node], e = rowptr[node + 1];
      int i = s;
      for (; i + 8 <= e; i += 8) {
        float2 t[8];
#pragma unroll
        for (int u = 0; u < 8; ++u) t[u] = Xv[(size_t)col[i + u] * 64 + lane];
#pragma unroll
        for (int u = 0; u < 8; ++u) { acc.x += t[u].x; acc.y += t[u].y; }
      }
      for (; i < e; ++i) {
        float2 v = Xv[(size_t)col[i] * 64 + lane];
        acc.x += v.x; acc.y += v.y;
      }
    }
    Xs[rr][2 * lane] = acc.x;
    Xs[rr][2 * lane + 1] = acc.y;
  }
#pragma unroll
  for (int it = 0; it < 4; ++it) {
    int l = tid + it * 256;
    int r = l >> 3, c4 = l & 7;
    *(float4*)&W1s[r][c4 * 4] = *(const float4*)&W1[r * 32 + c4 * 4];
  }
  if (tid < 96) W2s[tid] = W2[tid];
  if (tid < 32) b1s[tid] = b1[tid];
  if (tid < 3) b2s[tid] = b2[tid];
  __syncthreads();
  {
    int r = tid >> 2;
    int c0 = (tid & 3) * 8;
    float acc1[8];
#pragma unroll
    for (int j = 0; j < 8; ++j) acc1[j] = b1s[c0 + j];
#pragma unroll 2
    for (int k = 0; k < 128; ++k) {
      float xv = Xs[r][k];
      float4 wA = *(const float4*)&W1s[k][c0];
      float4 wB = *(const float4*)&W1s[k][c0 + 4];
      acc1[0] = fmaf(xv, wA.x, acc1[0]);
      acc1[1] = fmaf(xv, wA.y, acc1[1]);
      acc1[2] = fmaf(xv, wA.z, acc1[2]);
      acc1[3] = fmaf(xv, wA.w, acc1[3]);
      acc1[4] = fmaf(xv, wB.x, acc1[4]);
      acc1[5] = fmaf(xv, wB.y, acc1[5]);
      acc1[6] = fmaf(xv, wB.z, acc1[6]);
      acc1[7] = fmaf(xv, wB.w, acc1[7]);
    }
#pragma unroll
    for (int j = 0; j < 8; ++j) H1s[r][c0 + j] = fmaxf(acc1[j], 0.f);
  }
  __syncthreads();
  if (tid < 192) {
    int r = tid / 3, c = tid - (tid / 3) * 3;
    float accv = b2s[c];
#pragma unroll
    for (int k = 0; k < 32; ++k) accv = fmaf(H1s[r][k], W2s[k * 3 + c], accv);
    if (row0 + r < N) out[(size_t)(row0 + r) * 3 + c] = accv;
  }
}

// ============================ Host launcher ============================
extern "C" void kernel_launch(void* const* d_in, const int* in_sizes, int n_in,
                              void* d_out, int out_size, void* d_ws, size_t ws_size,
                              hipStream_t stream) {
  const float* x = (const float*)d_in[0];
  const int* ei = (const int*)d_in[1];
  const float* head_w1 = (const float*)d_in[2];
  const float* head_b1 = (const float*)d_in[3];
  const float* head_w2 = (const float*)d_in[4];
  const float* head_b2 = (const float*)d_in[5];
  const float* head_g = (const float*)d_in[6];
  const float* head_bt = (const float*)d_in[7];
  const float* res_w1 = (const float*)d_in[8];
  const float* res_b1 = (const float*)d_in[9];
  const float* res_w2 = (const float*)d_in[10];
  const float* res_b2 = (const float*)d_in[11];
  const float* res_g = (const float*)d_in[12];
  const float* res_bt = (const float*)d_in[13];
  const float* tail_w1 = (const float*)d_in[14];
  const float* tail_b1 = (const float*)d_in[15];
  const float* tail_w2 = (const float*)d_in[16];
  const float* tail_b2 = (const float*)d_in[17];

  const int N = in_sizes[0] / HDIM;
  const int E = in_sizes[1] / 2;
  const int NBUK = (N + 63) >> BSHIFT;
  const int* srcp = ei;
  const int* dstp = ei + E;

  char* base = (char*)d_ws;
  size_t off = 0;
  auto alloc = [&](size_t bytes) -> void* {
    void* p = base + off;
    off += (bytes + 255) & ~(size_t)255;
    return p;
  };
  float* B1 = (float*)alloc((size_t)N * HDIM * 4);
  float* B2 = (float*)alloc((size_t)N * HDIM * 4);
  float* B3 = (float*)alloc((size_t)N * HDIM * 4);
  int2* pairs = (int2*)alloc((size_t)E * 8);
  int* colb = (int*)alloc((size_t)E * 4);
  int* rowptr = (int*)alloc((size_t)(N + 1) * 4);
  int* bcnt = (int*)alloc((size_t)NBUK * 4);
  int* bbase = (int*)alloc((size_t)(NBUK + 1) * 4);
  int* bcur = (int*)alloc((size_t)NBUK * 4);
  float* S = (float*)alloc(8 * 256 * 4);  // raw {sum,sumsq} per producer
  _Float16* whi = (_Float16*)alloc(262144 * 2);
  _Float16* wlo = (_Float16*)alloc(262144 * 2);
  (void)ws_size; (void)n_in; (void)out_size;

  const float invN = 1.0f / (float)N;

  // ---- weight prep (single kernel) ----
  wprep_all<<<1024, 256, 0, stream>>>(head_w1, head_w2, res_w1, res_w2, whi, wlo);

  // ---- bucketed CSR build ----
  hipMemsetAsync(bcnt, 0, (size_t)NBUK * 4, stream);
  hipMemsetAsync(S, 0, 8 * 256 * 4, stream);
  bucket_hist<<<512, 256, 0, stream>>>(dstp, E, bcnt, NBUK);
  bucket_scan<<<1, 1024, 0, stream>>>(bcnt, bbase, bcur, NBUK, E);
  bucket_scatter<<<2048, 256, 0, stream>>>(srcp, dstp, E, bcur, pairs);
  csr_build<<<NBUK, 256, 0, stream>>>(pairs, bbase, rowptr, colb, N, NBUK);

  const int gridH = (N + 31) / 32, gridR = (N + 63) / 64;
  const _Float16* u1h[6]; const _Float16* u1l[6];
  const _Float16* u2h[6]; const _Float16* u2l[6];
  for (int u = 0; u < 6; ++u) {
    u1h[u] = whi + 65536 + u * 32768; u1l[u] = wlo + 65536 + u * 32768;
    u2h[u] = whi + 65536 + u * 32768 + 16384; u2l[u] = wlo + 65536 + u * 32768 + 16384;
  }

  // head: gather x (raw) -> MLP -> h_head(B1), statsH(S+0)
  fused_unit_kernel<1, 2, 0><<<gridH, 256, 0, stream>>>(
      x, B1, rowptr, colb, nullptr, nullptr, nullptr, invN,
      whi, wlo, head_b1, whi + 32768, wlo + 32768, head_b2, S, N);
  // yH = relu(bn(h_head)) -> B2   (materialized: consumed by u0 AND as block-1 identity)
  bn_relu_kernel<<<2048, 256, 0, stream>>>(B2, B1, S, head_g, head_bt, invN, nullptr, N * 32);
  // u0: gather yH raw -> h0(B3), stats0(S+256)
  fused_unit_kernel<2, 1, 0><<<gridR, 256, 0, stream>>>(
      B2, B3, rowptr, colb, nullptr, nullptr, nullptr, invN,
      u1h[0], u1l[0], res_b1 + 0 * HDIM, u2h[0], u2l[0], res_b2 + 0 * HDIM, S + 256, N);
  // u1: gather BN0(h0) -> h1(B1), stats1(S+512)
  fused_unit_kernel<2, 1, 1><<<gridR, 256, 0, stream>>>(
      B3, B1, rowptr, colb, S + 256, res_g + 0 * HDIM, res_bt + 0 * HDIM, invN,
      u1h[1], u1l[1], res_b1 + 1 * HDIM, u2h[1], u2l[1], res_b2 + 1 * HDIM, S + 512, N);
  // yB1 = relu(bn1(h1)) + yH -> B3
  bn_relu_kernel<<<2048, 256, 0, stream>>>(B3, B1, S + 512, res_g + 1 * HDIM,
                                           res_bt + 1 * HDIM, invN, B2, N * 32);
  // u2: gather yB1 raw -> h2(B1), stats2(S+768)
  fused_unit_kernel<2, 1, 0><<<gridR, 256, 0, stream>>>(
      B3, B1, rowptr, colb, nullptr, nullptr, nullptr, invN,
      u1h[2], u1l[2], res_b1 + 2 * HDIM, u2h[2], u2l[2], res_b2 + 2 * HDIM, S + 768, N);
  // u3: gather BN2(h2) -> h3(B2), stats3(S+1024)
  fused_unit_kernel<2, 1, 1><<<gridR, 256, 0, stream>>>(
      B1, B2, rowptr, colb, S + 768, res_g + 2 * HDIM, res_bt + 2 * HDIM, invN,
      u1h[3], u1l[3], res_b1 + 3 * HDIM, u2h[3], u2l[3], res_b2 + 3 * HDIM, S + 1024, N);
  // yB2 = relu(bn3(h3)) + yB1 -> B1
  bn_relu_kernel<<<2048, 256, 0, stream>>>(B1, B2, S + 1024, res_g + 3 * HDIM,
                                           res_bt + 3 * HDIM, invN, B3, N * 32);
  // u4: gather yB2 raw -> h4(B2), stats4(S+1280)
  fused_unit_kernel<2, 1, 0><<<gridR, 256, 0, stream>>>(
      B1, B2, rowptr, colb, nullptr, nullptr, nullptr, invN,
      u1h[4], u1l[4], res_b1 + 4 * HDIM, u2h[4], u2l[4], res_b2 + 4 * HDIM, S + 1280, N);
  // u5: gather BN4(h4) -> h5(B3), stats5(S+1536)
  fused_unit_kernel<2, 1, 1><<<gridR, 256, 0, stream>>>(
      B2, B3, rowptr, colb, S + 1280, res_g + 4 * HDIM, res_bt + 4 * HDIM, invN,
      u1h[5], u1l[5], res_b1 + 5 * HDIM, u2h[5], u2l[5], res_b2 + 5 * HDIM, S + 1536, N);
  // yB3 = relu(bn5(h5)) + yB2 -> B2
  bn_relu_kernel<<<2048, 256, 0, stream>>>(B2, B3, S + 1536, res_g + 5 * HDIM,
                                           res_bt + 5 * HDIM, invN, B1, N * 32);
  // tail: gather yB3 raw -> GIN(128->32->3) -> d_out
  tail_fused_kernel<<<gridR, 256, 0, stream>>>(B2, rowptr, colb, tail_w1, tail_b1,
                                               tail_w2, tail_b2, (float*)d_out, N);
}

// Round 6
// 1578.772 us; speedup vs baseline: 1.6363x; 1.6363x over previous
//
#include <hip/hip_runtime.h>
#include <cstdint>

#define HDIM 128
#define BN_EPS_F 1e-5f
#define BSHIFT 6  // 64 nodes per bucket

typedef _Float16 half8 __attribute__((ext_vector_type(8)));
typedef _Float16 half4v __attribute__((ext_vector_type(4)));
typedef _Float16 half2v __attribute__((ext_vector_type(2)));
typedef float f32x4 __attribute__((ext_vector_type(4)));

#define PA 136  // f16 pitch of A/H tiles
#define PW 72   // f16 pitch of W slabs

// ============================ Bucketed CSR build ============================
__global__ __launch_bounds__(256) void bucket_hist(const int* __restrict__ dst, int E,
                                                   int* __restrict__ bcnt, int NBUK) {
  __shared__ int lcnt[2048];
  int tid = threadIdx.x;
  for (int k = tid; k < 2048; k += 256) lcnt[k] = 0;
  __syncthreads();
  int i = blockIdx.x * blockDim.x + tid;
  int stride = gridDim.x * blockDim.x;
  for (; i < E; i += stride) atomicAdd(&lcnt[dst[i] >> BSHIFT], 1);
  __syncthreads();
  for (int k = tid; k < NBUK; k += 256) {
    int v = lcnt[k];
    if (v) atomicAdd(&bcnt[k], v);
  }
}

__global__ __launch_bounds__(1024) void bucket_scan(const int* __restrict__ bcnt,
    int* __restrict__ bbase, int* __restrict__ bcur, int NBUK, int E) {
  __shared__ int sd[1024];
  int t = threadIdx.x;
  int c0 = (2 * t < NBUK) ? bcnt[2 * t] : 0;
  int c1 = (2 * t + 1 < NBUK) ? bcnt[2 * t + 1] : 0;
  sd[t] = c0 + c1;
  __syncthreads();
  for (int o = 1; o < 1024; o <<= 1) {
    int v = (t >= o) ? sd[t - o] : 0;
    __syncthreads();
    sd[t] += v;
    __syncthreads();
  }
  int excl = sd[t] - (c0 + c1);
  if (2 * t < NBUK) { bbase[2 * t] = excl; bcur[2 * t] = excl; }
  if (2 * t + 1 < NBUK) { bbase[2 * t + 1] = excl + c0; bcur[2 * t + 1] = excl + c0; }
  if (t == 0) bbase[NBUK] = E;
}

__global__ __launch_bounds__(256) void bucket_scatter(const int* __restrict__ src,
    const int* __restrict__ dst, int E, int* __restrict__ bcur, int2* __restrict__ pairs) {
  int i = blockIdx.x * blockDim.x + threadIdx.x;
  int stride = gridDim.x * blockDim.x;
  for (; i < E; i += stride) {
    int d = dst[i];
    int p = atomicAdd(&bcur[d >> BSHIFT], 1);
    pairs[p] = make_int2(src[i], d);
  }
}

__global__ __launch_bounds__(256) void csr_build(const int2* __restrict__ pairs,
    const int* __restrict__ bbase, int* __restrict__ rowptr, int* __restrict__ col,
    int N, int NBUK) {
  __shared__ int cnt[64];
  __shared__ int off[65];
  int b = blockIdx.x, tid = threadIdx.x;
  int s = bbase[b], e = bbase[b + 1];
  if (tid < 64) cnt[tid] = 0;
  __syncthreads();
  for (int i = s + tid; i < e; i += 256) atomicAdd(&cnt[pairs[i].y & 63], 1);
  __syncthreads();
  if (tid == 0) {
    int r = 0;
    for (int k = 0; k < 64; ++k) { off[k] = r; r += cnt[k]; }
    off[64] = r;
  }
  __syncthreads();
  int node0 = b << BSHIFT;
  if (tid < 64) {
    int node = node0 + tid;
    if (node < N) rowptr[node] = s + off[tid];
    cnt[tid] = off[tid];  // reuse as cursor
  }
  __syncthreads();
  for (int i = s + tid; i < e; i += 256) {
    int2 p = pairs[i];
    int pos = atomicAdd(&cnt[p.y & 63], 1);
    col[s + pos] = p.x;
  }
  if (b == 0 && tid == 0) rowptr[N] = bbase[NBUK];
}

// ============================ Weight prep ============================
__global__ __launch_bounds__(256) void wprep_all(const float* __restrict__ hw1,
    const float* __restrict__ hw2, const float* __restrict__ rw1, const float* __restrict__ rw2,
    _Float16* __restrict__ hi, _Float16* __restrict__ lo) {
  int gid = blockIdx.x * 256 + threadIdx.x;
  if (gid >= 262144) return;
  const float* W;
  int K, Nn, off;
  if (gid < 32768) { W = hw1; K = 128; Nn = 256; off = 0; }
  else if (gid < 65536) { W = hw2; K = 256; Nn = 128; off = 32768; }
  else {
    int j = (gid - 65536) >> 14;
    int u = j >> 1;
    W = (j & 1) ? rw2 + (size_t)u * 16384 : rw1 + (size_t)u * 16384;
    K = 128; Nn = 128; off = 65536 + j * 16384;
  }
  int idx = gid - off;
  int n = idx / K, k = idx - n * K;
  float v = W[(size_t)k * Nn + n];
  _Float16 h = (_Float16)v;
  hi[gid] = h;
  lo[gid] = (_Float16)(v - (float)h);
}

// ============================ x -> f16 convert ============================
__global__ __launch_bounds__(256) void xcvt_kernel(const float* __restrict__ x,
    _Float16* __restrict__ y, int nv4) {
  int i = blockIdx.x * 256 + threadIdx.x;
  int stride = gridDim.x * 256;
  for (; i < nv4; i += stride) {
    float4 v = ((const float4*)x)[i];
    half4v h = {(_Float16)v.x, (_Float16)v.y, (_Float16)v.z, (_Float16)v.w};
    *(half4v*)&y[(size_t)i * 4] = h;
  }
}

// ============================ Aggregation (f16 in, f32 out) ============================
// One wave per node; lane covers cols {2l, 2l+1}. BNT=1: apply y=relu(a*h+b)
// (producer BN) to every gathered element. High occupancy (no LDS, low VGPR).
template <int BNT>
__global__ __launch_bounds__(256) void agg_f16_kernel(const _Float16* __restrict__ Y,
    float* __restrict__ A, const int* __restrict__ rowptr, const int* __restrict__ col,
    const float* __restrict__ pstats, const float* __restrict__ pg,
    const float* __restrict__ pbeta, float invN, int N) {
  int node = blockIdx.x * 4 + (threadIdx.x >> 6);
  if (node >= N) return;
  int lane = threadIdx.x & 63;
  float a0 = 1.f, a1 = 1.f, b0 = 0.f, b1 = 0.f;
  if constexpr (BNT) {
    int c0 = 2 * lane, c1 = c0 + 1;
    float m0 = pstats[c0] * invN, m1 = pstats[c1] * invN;
    float v0 = fmaxf(pstats[128 + c0] * invN - m0 * m0, 0.f);
    float v1 = fmaxf(pstats[128 + c1] * invN - m1 * m1, 0.f);
    a0 = pg[c0] * rsqrtf(v0 + BN_EPS_F);
    a1 = pg[c1] * rsqrtf(v1 + BN_EPS_F);
    b0 = pbeta[c0] - m0 * a0;
    b1 = pbeta[c1] - m1 * a1;
  }
  const half2v* Yv = (const half2v*)Y;  // index = node*64 + lane
  size_t rb = (size_t)node * 64 + lane;
  float2 acc;
  {
    half2v h = Yv[rb];
    float wx = (float)h[0], wy = (float)h[1];
    if constexpr (BNT) {
      wx = fmaxf(fmaf(wx, a0, b0), 0.f);
      wy = fmaxf(fmaf(wy, a1, b1), 0.f);
    }
    acc.x = wx; acc.y = wy;
  }
  int s = rowptr[node], e = rowptr[node + 1];
  int i = s;
  for (; i + 8 <= e; i += 8) {
    half2v t[8];
#pragma unroll
    for (int u = 0; u < 8; ++u) t[u] = Yv[(size_t)col[i + u] * 64 + lane];
#pragma unroll
    for (int u = 0; u < 8; ++u) {
      float wx = (float)t[u][0], wy = (float)t[u][1];
      if constexpr (BNT) {
        wx = fmaxf(fmaf(wx, a0, b0), 0.f);
        wy = fmaxf(fmaf(wy, a1, b1), 0.f);
      }
      acc.x += wx; acc.y += wy;
    }
  }
  for (; i < e; ++i) {
    half2v t = Yv[(size_t)col[i] * 64 + lane];
    float wx = (float)t[0], wy = (float)t[1];
    if constexpr (BNT) {
      wx = fmaxf(fmaf(wx, a0, b0), 0.f);
      wy = fmaxf(fmaf(wy, a1, b1), 0.f);
    }
    acc.x += wx; acc.y += wy;
  }
  ((float2*)A)[rb] = acc;
}

// ============================ MFMA MLP (f16x3 split) ============================
__device__ __forceinline__ void stage_w_slab(_Float16* dsth, _Float16* dstl,
    const _Float16* __restrict__ gh, const _Float16* __restrict__ gl, int stride, int koff) {
  int tid = threadIdx.x;
#pragma unroll
  for (int it = 0; it < 4; ++it) {
    int l = tid + it * 256;
    int r = l >> 3, ch = (l & 7) * 8;
    *(half8*)&dsth[r * PW + ch] = *(const half8*)&gh[(size_t)r * stride + koff + ch];
    *(half8*)&dstl[r * PW + ch] = *(const half8*)&gl[(size_t)r * stride + koff + ch];
  }
}

template <int MF>
__device__ __forceinline__ void gemm_slab(const _Float16* Sh, const _Float16* Sl,
    const _Float16* Wh, const _Float16* Wl, int rowbase, int l15, int l4, int wc, int slab,
    f32x4 (&acc)[MF][4]) {
#pragma unroll
  for (int split = 0; split < 3; ++split) {
    const _Float16* as = (split == 1) ? Sl : Sh;
    const _Float16* bs = (split == 2) ? Wl : Wh;
#pragma unroll
    for (int kf = 0; kf < 2; ++kf) {
      int ka = slab * 64 + kf * 32 + l4 * 8;
      int kw = kf * 32 + l4 * 8;
      half8 a[MF], b[4];
#pragma unroll
      for (int m = 0; m < MF; ++m)
        a[m] = *(const half8*)&as[(rowbase + m * 16 + l15) * PA + ka];
#pragma unroll
      for (int f = 0; f < 4; ++f)
        b[f] = *(const half8*)&bs[(wc * 64 + f * 16 + l15) * PW + kw];
#pragma unroll
      for (int m = 0; m < MF; ++m)
#pragma unroll
        for (int f = 0; f < 4; ++f)
          acc[m][f] = __builtin_amdgcn_mfma_f32_16x16x32_f16(a[m], b[f], acc[m][f], 0, 0, 0);
    }
  }
}

// In: f32 aggregated tile. Out: f16 raw h. stats: f32 col {sum,sumsq}.
template <int MF, int NH>
__global__ __launch_bounds__(256, 2) void mlp_kernel(
    const float* __restrict__ In, _Float16* __restrict__ Out,
    const _Float16* __restrict__ w1hi, const _Float16* __restrict__ w1lo,
    const float* __restrict__ b1,
    const _Float16* __restrict__ w2hi, const _Float16* __restrict__ w2lo,
    const float* __restrict__ b2, float* __restrict__ stats, int N) {
  constexpr int BM = MF * 32;
  __shared__ _Float16 Ab[2][BM * PA];
  __shared__ _Float16 Wb[2][128 * PW];
  __shared__ _Float16 Hb[NH == 2 ? 2 : 1][NH == 2 ? BM * PA : 1];

  const int tid = threadIdx.x;
  const int wave = tid >> 6, lane = tid & 63;
  const int wr = wave >> 1, wc = wave & 1;
  const int l15 = lane & 15, l4 = lane >> 4;
  const int row0 = blockIdx.x * BM;
  const int rowbase = wr * (MF * 16);

  // stage + hi/lo split of A tile
#pragma unroll
  for (int it = 0; it < BM / 8; ++it) {
    int l = tid + it * 256;
    int r = l >> 5, c4 = (l & 31) * 4;
    float4 v = make_float4(0.f, 0.f, 0.f, 0.f);
    if (row0 + r < N) v = *(const float4*)&In[(size_t)(row0 + r) * HDIM + c4];
    half4v hh, ll;
    hh.x = (_Float16)v.x; ll.x = (_Float16)(v.x - (float)hh.x);
    hh.y = (_Float16)v.y; ll.y = (_Float16)(v.y - (float)hh.y);
    hh.z = (_Float16)v.z; ll.z = (_Float16)(v.z - (float)hh.z);
    hh.w = (_Float16)v.w; ll.w = (_Float16)(v.w - (float)hh.w);
    *(half4v*)&Ab[0][r * PA + c4] = hh;
    *(half4v*)&Ab[1][r * PA + c4] = ll;
  }

  _Float16 *Hh, *Hl;
  if constexpr (NH == 2) { Hh = Hb[0]; Hl = Hb[1]; }
  else { Hh = Ab[0]; Hl = Ab[1]; }

  f32x4 acc2[MF][4];
#pragma unroll
  for (int f = 0; f < 4; ++f) {
    float bv = b2[wc * 64 + f * 16 + l15];
#pragma unroll
    for (int m = 0; m < MF; ++m) acc2[m][f] = (f32x4){bv, bv, bv, bv};
  }

  for (int h = 0; h < NH; ++h) {
    f32x4 acc1[MF][4];
#pragma unroll
    for (int f = 0; f < 4; ++f) {
      float bv = b1[h * 128 + wc * 64 + f * 16 + l15];
#pragma unroll
      for (int m = 0; m < MF; ++m) acc1[m][f] = (f32x4){bv, bv, bv, bv};
    }
#pragma unroll
    for (int slab = 0; slab < 2; ++slab) {
      __syncthreads();  // A staged / prior W readers done
      stage_w_slab(Wb[0], Wb[1], w1hi + (size_t)h * 128 * 128, w1lo + (size_t)h * 128 * 128,
                   128, slab * 64);
      __syncthreads();
      gemm_slab<MF>(Ab[0], Ab[1], Wb[0], Wb[1], rowbase, l15, l4, wc, slab, acc1);
    }
    __syncthreads();  // all A/W reads done (alias safety for NH==1)
    // ReLU + hi/lo split -> H  (C/D: row=(lane>>4)*4+reg, col=lane&15)
#pragma unroll
    for (int m = 0; m < MF; ++m)
#pragma unroll
      for (int f = 0; f < 4; ++f)
#pragma unroll
        for (int r = 0; r < 4; ++r) {
          float v = fmaxf(acc1[m][f][r], 0.f);
          _Float16 hh = (_Float16)v;
          int row = rowbase + m * 16 + l4 * 4 + r;
          int ck = wc * 64 + f * 16 + l15;
          Hh[row * PA + ck] = hh;
          Hl[row * PA + ck] = (_Float16)(v - (float)hh);
        }
#pragma unroll
    for (int slab = 0; slab < 2; ++slab) {
      __syncthreads();
      stage_w_slab(Wb[0], Wb[1], w2hi, w2lo, NH * 128, h * 128 + slab * 64);
      __syncthreads();
      gemm_slab<MF>(Hh, Hl, Wb[0], Wb[1], rowbase, l15, l4, wc, slab, acc2);
    }
  }

  // epilogue: f16 store + BN raw-stat partials (exact f32)
  __syncthreads();
  float* psum = (float*)&Wb[0][0];
  float* psq = psum + 256;
#pragma unroll
  for (int f = 0; f < 4; ++f) {
    float s = 0.f, q = 0.f;
#pragma unroll
    for (int m = 0; m < MF; ++m)
#pragma unroll
      for (int r = 0; r < 4; ++r) {
        int grow = row0 + rowbase + m * 16 + l4 * 4 + r;
        float v = acc2[m][f][r];
        if (grow < N) {
          Out[(size_t)grow * HDIM + wc * 64 + f * 16 + l15] = (_Float16)v;
          s += v;
          q += v * v;
        }
      }
    s += __shfl_xor(s, 16); q += __shfl_xor(q, 16);
    s += __shfl_xor(s, 32); q += __shfl_xor(q, 32);
    if (l4 == 0) {
      psum[wr * 128 + wc * 64 + f * 16 + l15] = s;
      psq[wr * 128 + wc * 64 + f * 16 + l15] = q;
    }
  }
  __syncthreads();
  if (tid < 128) {
    atomicAdd(&stats[tid], psum[tid] + psum[128 + tid]);
    atomicAdd(&stats[128 + tid], psq[tid] + psq[128 + tid]);
  }
}

// ============================ BN apply (+identity / +dual BN), f16 io ============
// DUAL=1: out = relu(bn1(h1)) + relu(bn2(h2))   (h2 = raw producer output)
// DUAL=0: out = relu(bn1(h1)) + y2              (y2 = materialized f16)
template <int DUAL>
__global__ __launch_bounds__(256) void bnrelu_kernel(
    const _Float16* __restrict__ h1, const float* __restrict__ s1,
    const float* __restrict__ g1, const float* __restrict__ bt1,
    const _Float16* __restrict__ h2, const float* __restrict__ s2,
    const float* __restrict__ g2, const float* __restrict__ bt2,
    _Float16* __restrict__ out, float invN, int nv8) {
  int tid = blockIdx.x * 256 + threadIdx.x;
  int c8 = (tid & 15) * 8;  // stride (2048*256) % 16 == 0 keeps col set per-thread
  float a1[8], r1[8], a2[8], r2[8];
#pragma unroll
  for (int j = 0; j < 8; ++j) {
    int c = c8 + j;
    float m = s1[c] * invN;
    float v = fmaxf(s1[128 + c] * invN - m * m, 0.f);
    a1[j] = g1[c] * rsqrtf(v + BN_EPS_F);
    r1[j] = bt1[c] - m * a1[j];
    if constexpr (DUAL) {
      float m2 = s2[c] * invN;
      float v2 = fmaxf(s2[128 + c] * invN - m2 * m2, 0.f);
      a2[j] = g2[c] * rsqrtf(v2 + BN_EPS_F);
      r2[j] = bt2[c] - m2 * a2[j];
    } else {
      a2[j] = 0.f; r2[j] = 0.f;
    }
  }
  int stride = gridDim.x * 256;
  for (int i = tid; i < nv8; i += stride) {
    half8 u = ((const half8*)h1)[i];
    half8 v = ((const half8*)h2)[i];
    half8 o;
#pragma unroll
    for (int j = 0; j < 8; ++j) {
      float y = fmaxf(fmaf((float)u[j], a1[j], r1[j]), 0.f);
      if constexpr (DUAL) y += fmaxf(fmaf((float)v[j], a2[j], r2[j]), 0.f);
      else y += (float)v[j];
      o[j] = (_Float16)y;
    }
    ((half8*)out)[i] = o;
  }
}

// ============================ Tail (reads f32 agg, GIN 128->32->3) ============================
__global__ __launch_bounds__(256, 1) void tail_kernel(
    const float* __restrict__ A, const float* __restrict__ W1, const float* __restrict__ b1,
    const float* __restrict__ W2, const float* __restrict__ b2, float* __restrict__ out, int N) {
  __shared__ float Xs[64][132];
  __shared__ float W1s[128][32];
  __shared__ float H1s[64][36];
  __shared__ float W2s[96];
  __shared__ float b1s[32];
  __shared__ float b2s[3];
  int tid = threadIdx.x;
  int row0 = blockIdx.x * 64;
#pragma unroll
  for (int it = 0; it < 8; ++it) {
    int l = tid + it * 256, r = l >> 5, c4 = l & 31;
    float4 v = make_float4(0.f, 0.f, 0.f, 0.f);
    if (row0 + r < N) v = *(const float4*)&A[(size_t)(row0 + r) * HDIM + c4 * 4];
    *(float4*)&Xs[r][c4 * 4] = v;
  }
#pragma unroll
  for (int it = 0; it < 4; ++it) {
    int l = tid + it * 256;
    int r = l >> 3, c4 = l & 7;
    *(float4*)&W1s[r][c4 * 4] = *(const float4*)&W1[r * 32 + c4 * 4];
  }
  if (tid < 96) W2s[tid] = W2[tid];
  if (tid < 32) b1s[tid] = b1[tid];
  if (tid < 3) b2s[tid] = b2[tid];
  __syncthreads();
  {
    int r = tid >> 2;
    int c0 = (tid & 3) * 8;
    float acc1[8];
#pragma unroll
    for (int j = 0; j < 8; ++j) acc1[j] = b1s[c0 + j];
#pragma unroll 2
    for (int k = 0; k < 128; ++k) {
      float xv = Xs[r][k];
      float4 wA = *(const float4*)&W1s[k][c0];
      float4 wB = *(const float4*)&W1s[k][c0 + 4];
      acc1[0] = fmaf(xv, wA.x, acc1[0]);
      acc1[1] = fmaf(xv, wA.y, acc1[1]);
      acc1[2] = fmaf(xv, wA.z, acc1[2]);
      acc1[3] = fmaf(xv, wA.w, acc1[3]);
      acc1[4] = fmaf(xv, wB.x, acc1[4]);
      acc1[5] = fmaf(xv, wB.y, acc1[5]);
      acc1[6] = fmaf(xv, wB.z, acc1[6]);
      acc1[7] = fmaf(xv, wB.w, acc1[7]);
    }
#pragma unroll
    for (int j = 0; j < 8; ++j) H1s[r][c0 + j] = fmaxf(acc1[j], 0.f);
  }
  __syncthreads();
  if (tid < 192) {
    int r = tid / 3, c = tid - (tid / 3) * 3;
    float accv = b2s[c];
#pragma unroll
    for (int k = 0; k < 32; ++k) accv = fmaf(H1s[r][k], W2s[k * 3 + c], accv);
    if (row0 + r < N) out[(size_t)(row0 + r) * 3 + c] = accv;
  }
}

// ============================ Host launcher ============================
extern "C" void kernel_launch(void* const* d_in, const int* in_sizes, int n_in,
                              void* d_out, int out_size, void* d_ws, size_t ws_size,
                              hipStream_t stream) {
  const float* x = (const float*)d_in[0];
  const int* ei = (const int*)d_in[1];
  const float* head_w1 = (const float*)d_in[2];
  const float* head_b1 = (const float*)d_in[3];
  const float* head_w2 = (const float*)d_in[4];
  const float* head_b2 = (const float*)d_in[5];
  const float* head_g = (const float*)d_in[6];
  const float* head_bt = (const float*)d_in[7];
  const float* res_w1 = (const float*)d_in[8];
  const float* res_b1 = (const float*)d_in[9];
  const float* res_w2 = (const float*)d_in[10];
  const float* res_b2 = (const float*)d_in[11];
  const float* res_g = (const float*)d_in[12];
  const float* res_bt = (const float*)d_in[13];
  const float* tail_w1 = (const float*)d_in[14];
  const float* tail_b1 = (const float*)d_in[15];
  const float* tail_w2 = (const float*)d_in[16];
  const float* tail_b2 = (const float*)d_in[17];

  const int N = in_sizes[0] / HDIM;
  const int E = in_sizes[1] / 2;
  const int NBUK = (N + 63) >> BSHIFT;
  const int* srcp = ei;
  const int* dstp = ei + E;

  char* base = (char*)d_ws;
  size_t off = 0;
  auto alloc = [&](size_t bytes) -> void* {
    void* p = base + off;
    off += (bytes + 255) & ~(size_t)255;
    return p;
  };
  _Float16* F0 = (_Float16*)alloc((size_t)N * HDIM * 2);
  _Float16* F1 = (_Float16*)alloc((size_t)N * HDIM * 2);
  _Float16* F2 = (_Float16*)alloc((size_t)N * HDIM * 2);
  _Float16* F3 = (_Float16*)alloc((size_t)N * HDIM * 2);
  float* A = (float*)alloc((size_t)N * HDIM * 4);
  int* colb = (int*)alloc((size_t)E * 4);
  int* rowptr = (int*)alloc((size_t)(N + 1) * 4);
  int* bcnt = (int*)alloc((size_t)NBUK * 4);
  int* bbase = (int*)alloc((size_t)(NBUK + 1) * 4);
  int* bcur = (int*)alloc((size_t)NBUK * 4);
  float* S = (float*)alloc(8 * 256 * 4);
  _Float16* whi = (_Float16*)alloc(262144 * 2);
  _Float16* wlo = (_Float16*)alloc(262144 * 2);
  // aliases (disjoint lifetimes): pairs lives only during CSR build, in A's slot
  // (A first written by head agg, after csr_build). X16 (f16 x) lives only until
  // head agg done; F3 first written at yB1. E*8 = 12.8MB <= N*HDIM*4 = 51.2MB OK.
  int2* pairs = (int2*)A;
  _Float16* X16 = F3;
  (void)ws_size; (void)n_in; (void)out_size;

  const float invN = 1.0f / (float)N;
  const int aggGrid = (N + 3) / 4;
  const int gridH = (N + 31) / 32, gridR = (N + 63) / 64;
  const int nv8 = N * (HDIM / 8);

  // ---- prep ----
  wprep_all<<<1024, 256, 0, stream>>>(head_w1, head_w2, res_w1, res_w2, whi, wlo);
  xcvt_kernel<<<2048, 256, 0, stream>>>(x, X16, N * (HDIM / 4));
  hipMemsetAsync(bcnt, 0, (size_t)NBUK * 4, stream);
  hipMemsetAsync(S, 0, 8 * 256 * 4, stream);
  bucket_hist<<<512, 256, 0, stream>>>(dstp, E, bcnt, NBUK);
  bucket_scan<<<1, 1024, 0, stream>>>(bcnt, bbase, bcur, NBUK, E);
  bucket_scatter<<<2048, 256, 0, stream>>>(srcp, dstp, E, bcur, pairs);
  csr_build<<<NBUK, 256, 0, stream>>>(pairs, bbase, rowptr, colb, N, NBUK);

  const _Float16* u1h[6]; const _Float16* u1l[6];
  const _Float16* u2h[6]; const _Float16* u2l[6];
  for (int u = 0; u < 6; ++u) {
    u1h[u] = whi + 65536 + u * 32768; u1l[u] = wlo + 65536 + u * 32768;
    u2h[u] = whi + 65536 + u * 32768 + 16384; u2l[u] = wlo + 65536 + u * 32768 + 16384;
  }

  // ---- head: agg(x16) -> A ; MLP -> F0 (h_head), statsH(S) ----
  agg_f16_kernel<0><<<aggGrid, 256, 0, stream>>>(X16, A, rowptr, colb,
      nullptr, nullptr, nullptr, invN, N);
  mlp_kernel<1, 2><<<gridH, 256, 0, stream>>>(A, F0, whi, wlo, head_b1,
      whi + 32768, wlo + 32768, head_b2, S, N);
  // ---- u0: aggBN(F0; statsH) -> A ; MLP -> F1 (h0), stats0 ----
  agg_f16_kernel<1><<<aggGrid, 256, 0, stream>>>(F0, A, rowptr, colb,
      S, head_g, head_bt, invN, N);
  mlp_kernel<2, 1><<<gridR, 256, 0, stream>>>(A, F1, u1h[0], u1l[0], res_b1,
      u2h[0], u2l[0], res_b2, S + 256, N);
  // ---- u1: aggBN(F1; stats0) -> A ; MLP -> F2 (h1), stats1 ----
  agg_f16_kernel<1><<<aggGrid, 256, 0, stream>>>(F1, A, rowptr, colb,
      S + 256, res_g, res_bt, invN, N);
  mlp_kernel<2, 1><<<gridR, 256, 0, stream>>>(A, F2, u1h[1], u1l[1], res_b1 + HDIM,
      u2h[1], u2l[1], res_b2 + HDIM, S + 512, N);
  // ---- yB1 = relu(bn1(h1)) + relu(bnH(h_head)) -> F3 ----
  bnrelu_kernel<1><<<2048, 256, 0, stream>>>(F2, S + 512, res_g + HDIM, res_bt + HDIM,
      F0, S, head_g, head_bt, F3, invN, nv8);
  // ---- u2: agg(F3) -> A ; MLP -> F0 (h2), stats2 ----
  agg_f16_kernel<0><<<aggGrid, 256, 0, stream>>>(F3, A, rowptr, colb,
      nullptr, nullptr, nullptr, invN, N);
  mlp_kernel<2, 1><<<gridR, 256, 0, stream>>>(A, F0, u1h[2], u1l[2], res_b1 + 2 * HDIM,
      u2h[2], u2l[2], res_b2 + 2 * HDIM, S + 768, N);
  // ---- u3: aggBN(F0; stats2) -> A ; MLP -> F1 (h3), stats3 ----
  agg_f16_kernel<1><<<aggGrid, 256, 0, stream>>>(F0, A, rowptr, colb,
      S + 768, res_g + 2 * HDIM, res_bt + 2 * HDIM, invN, N);
  mlp_kernel<2, 1><<<gridR, 256, 0, stream>>>(A, F1, u1h[3], u1l[3], res_b1 + 3 * HDIM,
      u2h[3], u2l[3], res_b2 + 3 * HDIM, S + 1024, N);
  // ---- yB2 = relu(bn3(h3)) + yB1 -> F2 ----
  bnrelu_kernel<0><<<2048, 256, 0, stream>>>(F1, S + 1024, res_g + 3 * HDIM,
      res_bt + 3 * HDIM, F3, nullptr, nullptr, nullptr, F2, invN, nv8);
  // ---- u4: agg(F2) -> A ; MLP -> F0 (h4), stats4 ----
  agg_f16_kernel<0><<<aggGrid, 256, 0, stream>>>(F2, A, rowptr, colb,
      nullptr, nullptr, nullptr, invN, N);
  mlp_kernel<2, 1><<<gridR, 256, 0, stream>>>(A, F0, u1h[4], u1l[4], res_b1 + 4 * HDIM,
      u2h[4], u2l[4], res_b2 + 4 * HDIM, S + 1280, N);
  // ---- u5: aggBN(F0; stats4) -> A ; MLP -> F1 (h5), stats5 ----
  agg_f16_kernel<1><<<aggGrid, 256, 0, stream>>>(F0, A, rowptr, colb,
      S + 1280, res_g + 4 * HDIM, res_bt + 4 * HDIM, invN, N);
  mlp_kernel<2, 1><<<gridR, 256, 0, stream>>>(A, F1, u1h[5], u1l[5], res_b1 + 5 * HDIM,
      u2h[5], u2l[5], res_b2 + 5 * HDIM, S + 1536, N);
  // ---- yB3 = relu(bn5(h5)) + yB2 -> F3 ----
  bnrelu_kernel<0><<<2048, 256, 0, stream>>>(F1, S + 1536, res_g + 5 * HDIM,
      res_bt + 5 * HDIM, F2, nullptr, nullptr, nullptr, F3, invN, nv8);
  // ---- tail: agg(F3) -> A ; GIN(128->32->3) -> out ----
  agg_f16_kernel<0><<<aggGrid, 256, 0, stream>>>(F3, A, rowptr, colb,
      nullptr, nullptr, nullptr, invN, N);
  tail_kernel<<<gridR, 256, 0, stream>>>(A, tail_w1, tail_b1, tail_w2, tail_b2,
                                         (float*)d_out, N);
}

// Round 8
// 1331.825 us; speedup vs baseline: 1.9397x; 1.1854x over previous
//
#include <hip/hip_runtime.h>
#include <cstdint>

#define HDIM 128
#define BN_EPS_F 1e-5f
#define CSH 8            // 256 nodes per coarse region
#define CMAX 512         // max coarse regions (N <= 131072)
#define CHUNK 4096       // edges per binning block

typedef _Float16 half8 __attribute__((ext_vector_type(8)));
typedef _Float16 half4v __attribute__((ext_vector_type(4)));
typedef _Float16 half2v __attribute__((ext_vector_type(2)));
typedef float f32x4 __attribute__((ext_vector_type(4)));

#define PA 136  // f16 pitch of A/H tiles
#define PW 72   // f16 pitch of W slabs

// ============================ Two-level binned CSR build ============================
// Key insight: never do random 4-8B global writes (R6: 86MB amplified, 240us).
// Instead: exact LDS binning per 4096-edge chunk, then contiguous run copies.

__global__ __launch_bounds__(256) void coarse_hist(const int* __restrict__ dst, int E,
                                                   int* __restrict__ gcnt) {
  __shared__ int l[CMAX];
  int tid = threadIdx.x;
  for (int k = tid; k < CMAX; k += 256) l[k] = 0;
  __syncthreads();
  int i = blockIdx.x * blockDim.x + tid;
  int stride = gridDim.x * blockDim.x;
  for (; i < E; i += stride) atomicAdd(&l[dst[i] >> CSH], 1);
  __syncthreads();
  for (int k = tid; k < CMAX; k += 256) {
    int v = l[k];
    if (v) atomicAdd(&gcnt[k], v);
  }
}

// single block, 256 threads: exclusive scan of gcnt[512] -> gbase, gcur
__global__ __launch_bounds__(256) void coarse_scan(const int* __restrict__ gcnt,
    int* __restrict__ gbase, int* __restrict__ gcur, int E) {
  __shared__ int sd[256];
  int t = threadIdx.x;
  int c0 = gcnt[2 * t], c1 = gcnt[2 * t + 1];
  sd[t] = c0 + c1;
  __syncthreads();
  for (int o = 1; o < 256; o <<= 1) {
    int v = (t >= o) ? sd[t - o] : 0;
    __syncthreads();
    sd[t] += v;
    __syncthreads();
  }
  int excl = sd[t] - (c0 + c1);
  gbase[2 * t] = excl; gcur[2 * t] = excl;
  gbase[2 * t + 1] = excl + c0; gcur[2 * t + 1] = excl + c0;
  if (t == 0) gbase[CMAX] = E;
}

// chunk -> LDS exact binning -> contiguous run copies. packed = (src<<8)|(dst&255)
__global__ __launch_bounds__(256) void bin_chunk(const int* __restrict__ src,
    const int* __restrict__ dst, int E, int* __restrict__ gcur,
    unsigned int* __restrict__ binned) {
  __shared__ int cnt[CMAX];
  __shared__ int ofs[CMAX];
  __shared__ int cur[CMAX];
  __shared__ int gb[CMAX];
  __shared__ int sd[256];
  __shared__ unsigned int data[CHUNK];
  __shared__ unsigned short keyv[CHUNK];
  const int tid = threadIdx.x;
  const int c0e = blockIdx.x * CHUNK;
  const int n = min(CHUNK, E - c0e);

  int ss[CHUNK / 256], dd[CHUNK / 256];
#pragma unroll
  for (int k = 0; k < CHUNK / 256; ++k) {
    int idx = c0e + k * 256 + tid;
    if (idx < E) { ss[k] = src[idx]; dd[k] = dst[idx]; }
    else dd[k] = -1;
  }
  for (int k = tid; k < CMAX; k += 256) cnt[k] = 0;
  __syncthreads();
#pragma unroll
  for (int k = 0; k < CHUNK / 256; ++k)
    if (dd[k] >= 0) atomicAdd(&cnt[dd[k] >> CSH], 1);
  __syncthreads();
  // exclusive scan of cnt[512] (pair trick)
  {
    int a = cnt[2 * tid], b = cnt[2 * tid + 1];
    sd[tid] = a + b;
    __syncthreads();
    for (int o = 1; o < 256; o <<= 1) {
      int v = (tid >= o) ? sd[tid - o] : 0;
      __syncthreads();
      sd[tid] += v;
      __syncthreads();
    }
    int excl = sd[tid] - (a + b);
    ofs[2 * tid] = excl; cur[2 * tid] = excl;
    ofs[2 * tid + 1] = excl + a; cur[2 * tid + 1] = excl + a;
  }
  __syncthreads();
#pragma unroll
  for (int k = 0; k < CHUNK / 256; ++k) {
    if (dd[k] >= 0) {
      int key = dd[k] >> CSH;
      int p = atomicAdd(&cur[key], 1);
      data[p] = ((unsigned int)ss[k] << CSH) | (unsigned int)(dd[k] & ((1 << CSH) - 1));
      keyv[p] = (unsigned short)key;
    }
  }
  __syncthreads();
  for (int j = tid; j < CMAX; j += 256) {
    int c = cnt[j];
    gb[j] = c ? atomicAdd(&gcur[j], c) : 0;
  }
  __syncthreads();
  for (int i = tid; i < n; i += 256) {
    int k = keyv[i];
    binned[gb[k] + (i - ofs[k])] = data[i];
  }
}

// one block per coarse region: rowptr slice + col within L2-resident window
__global__ __launch_bounds__(256) void region_build(const unsigned int* __restrict__ binned,
    const int* __restrict__ gbase, int* __restrict__ rowptr, int* __restrict__ col,
    int N, int E) {
  __shared__ int cnt[256];
  __shared__ int off[256];
  __shared__ int sd[256];
  const int b = blockIdx.x, tid = threadIdx.x;
  const int s = gbase[b], e = gbase[b + 1];
  cnt[tid] = 0;
  __syncthreads();
  for (int i = s + tid; i < e; i += 256)
    atomicAdd(&cnt[binned[i] & 255], 1);
  __syncthreads();
  // exclusive scan 256
  int c = cnt[tid];
  sd[tid] = c;
  __syncthreads();
  for (int o = 1; o < 256; o <<= 1) {
    int v = (tid >= o) ? sd[tid - o] : 0;
    __syncthreads();
    sd[tid] += v;
    __syncthreads();
  }
  off[tid] = sd[tid] - c;
  __syncthreads();
  int node = (b << CSH) + tid;
  if (node < N) rowptr[node] = s + off[tid];
  cnt[tid] = off[tid];  // reuse as cursor
  __syncthreads();
  for (int i = s + tid; i < e; i += 256) {
    unsigned int v = binned[i];
    int p = atomicAdd(&cnt[v & 255], 1);
    col[s + p] = (int)(v >> CSH);
  }
  if (b == 0 && tid == 0) rowptr[N] = E;
}

// ============================ Weight prep ============================
__global__ __launch_bounds__(256) void wprep_all(const float* __restrict__ hw1,
    const float* __restrict__ hw2, const float* __restrict__ rw1, const float* __restrict__ rw2,
    _Float16* __restrict__ hi, _Float16* __restrict__ lo) {
  int gid = blockIdx.x * 256 + threadIdx.x;
  if (gid >= 262144) return;
  const float* W;
  int K, Nn, off;
  if (gid < 32768) { W = hw1; K = 128; Nn = 256; off = 0; }
  else if (gid < 65536) { W = hw2; K = 256; Nn = 128; off = 32768; }
  else {
    int j = (gid - 65536) >> 14;
    int u = j >> 1;
    W = (j & 1) ? rw2 + (size_t)u * 16384 : rw1 + (size_t)u * 16384;
    K = 128; Nn = 128; off = 65536 + j * 16384;
  }
  int idx = gid - off;
  int n = idx / K, k = idx - n * K;
  float v = W[(size_t)k * Nn + n];
  _Float16 h = (_Float16)v;
  hi[gid] = h;
  lo[gid] = (_Float16)(v - (float)h);
}

// ============================ x -> f16 convert ============================
__global__ __launch_bounds__(256) void xcvt_kernel(const float* __restrict__ x,
    _Float16* __restrict__ y, int nv4) {
  int i = blockIdx.x * 256 + threadIdx.x;
  int stride = gridDim.x * 256;
  for (; i < nv4; i += stride) {
    float4 v = ((const float4*)x)[i];
    half4v h = {(_Float16)v.x, (_Float16)v.y, (_Float16)v.z, (_Float16)v.w};
    *(half4v*)&y[(size_t)i * 4] = h;
  }
}

// ============================ Aggregation (f16 in, f32 out) ============================
template <int BNT>
__global__ __launch_bounds__(256) void agg_f16_kernel(const _Float16* __restrict__ Y,
    float* __restrict__ A, const int* __restrict__ rowptr, const int* __restrict__ col,
    const float* __restrict__ pstats, const float* __restrict__ pg,
    const float* __restrict__ pbeta, float invN, int N) {
  int node = blockIdx.x * 4 + (threadIdx.x >> 6);
  if (node >= N) return;
  int lane = threadIdx.x & 63;
  float a0 = 1.f, a1 = 1.f, b0 = 0.f, b1 = 0.f;
  if constexpr (BNT) {
    int c0 = 2 * lane, c1 = c0 + 1;
    float m0 = pstats[c0] * invN, m1 = pstats[c1] * invN;
    float v0 = fmaxf(pstats[128 + c0] * invN - m0 * m0, 0.f);
    float v1 = fmaxf(pstats[128 + c1] * invN - m1 * m1, 0.f);
    a0 = pg[c0] * rsqrtf(v0 + BN_EPS_F);
    a1 = pg[c1] * rsqrtf(v1 + BN_EPS_F);
    b0 = pbeta[c0] - m0 * a0;
    b1 = pbeta[c1] - m1 * a1;
  }
  const half2v* Yv = (const half2v*)Y;
  size_t rb = (size_t)node * 64 + lane;
  float2 acc;
  {
    half2v h = Yv[rb];
    float wx = (float)h[0], wy = (float)h[1];
    if constexpr (BNT) {
      wx = fmaxf(fmaf(wx, a0, b0), 0.f);
      wy = fmaxf(fmaf(wy, a1, b1), 0.f);
    }
    acc.x = wx; acc.y = wy;
  }
  int s = rowptr[node], e = rowptr[node + 1];
  int i = s;
  for (; i + 8 <= e; i += 8) {
    half2v t[8];
#pragma unroll
    for (int u = 0; u < 8; ++u) t[u] = Yv[(size_t)col[i + u] * 64 + lane];
#pragma unroll
    for (int u = 0; u < 8; ++u) {
      float wx = (float)t[u][0], wy = (float)t[u][1];
      if constexpr (BNT) {
        wx = fmaxf(fmaf(wx, a0, b0), 0.f);
        wy = fmaxf(fmaf(wy, a1, b1), 0.f);
      }
      acc.x += wx; acc.y += wy;
    }
  }
  for (; i < e; ++i) {
    half2v t = Yv[(size_t)col[i] * 64 + lane];
    float wx = (float)t[0], wy = (float)t[1];
    if constexpr (BNT) {
      wx = fmaxf(fmaf(wx, a0, b0), 0.f);
      wy = fmaxf(fmaf(wy, a1, b1), 0.f);
    }
    acc.x += wx; acc.y += wy;
  }
  ((float2*)A)[rb] = acc;
}

// ============================ MFMA MLP (f16x3 split) ============================
__device__ __forceinline__ void stage_w_slab(_Float16* dsth, _Float16* dstl,
    const _Float16* __restrict__ gh, const _Float16* __restrict__ gl, int stride, int koff) {
  int tid = threadIdx.x;
#pragma unroll
  for (int it = 0; it < 4; ++it) {
    int l = tid + it * 256;
    int r = l >> 3, ch = (l & 7) * 8;
    *(half8*)&dsth[r * PW + ch] = *(const half8*)&gh[(size_t)r * stride + koff + ch];
    *(half8*)&dstl[r * PW + ch] = *(const half8*)&gl[(size_t)r * stride + koff + ch];
  }
}

template <int MF>
__device__ __forceinline__ void gemm_slab(const _Float16* Sh, const _Float16* Sl,
    const _Float16* Wh, const _Float16* Wl, int rowbase, int l15, int l4, int wc, int slab,
    f32x4 (&acc)[MF][4]) {
#pragma unroll
  for (int split = 0; split < 3; ++split) {
    const _Float16* as = (split == 1) ? Sl : Sh;
    const _Float16* bs = (split == 2) ? Wl : Wh;
#pragma unroll
    for (int kf = 0; kf < 2; ++kf) {
      int ka = slab * 64 + kf * 32 + l4 * 8;
      int kw = kf * 32 + l4 * 8;
      half8 a[MF], b[4];
#pragma unroll
      for (int m = 0; m < MF; ++m)
        a[m] = *(const half8*)&as[(rowbase + m * 16 + l15) * PA + ka];
#pragma unroll
      for (int f = 0; f < 4; ++f)
        b[f] = *(const half8*)&bs[(wc * 64 + f * 16 + l15) * PW + kw];
#pragma unroll
      for (int m = 0; m < MF; ++m)
#pragma unroll
        for (int f = 0; f < 4; ++f)
          acc[m][f] = __builtin_amdgcn_mfma_f32_16x16x32_f16(a[m], b[f], acc[m][f], 0, 0, 0);
    }
  }
}

template <int MF, int NH>
__global__ __launch_bounds__(256, 2) void mlp_kernel(
    const float* __restrict__ In, _Float16* __restrict__ Out,
    const _Float16* __restrict__ w1hi, const _Float16* __restrict__ w1lo,
    const float* __restrict__ b1,
    const _Float16* __restrict__ w2hi, const _Float16* __restrict__ w2lo,
    const float* __restrict__ b2, float* __restrict__ stats, int N) {
  constexpr int BM = MF * 32;
  __shared__ _Float16 Ab[2][BM * PA];
  __shared__ _Float16 Wb[2][128 * PW];
  __shared__ _Float16 Hb[NH == 2 ? 2 : 1][NH == 2 ? BM * PA : 1];

  const int tid = threadIdx.x;
  const int wave = tid >> 6, lane = tid & 63;
  const int wr = wave >> 1, wc = wave & 1;
  const int l15 = lane & 15, l4 = lane >> 4;
  const int row0 = blockIdx.x * BM;
  const int rowbase = wr * (MF * 16);

#pragma unroll
  for (int it = 0; it < BM / 8; ++it) {
    int l = tid + it * 256;
    int r = l >> 5, c4 = (l & 31) * 4;
    float4 v = make_float4(0.f, 0.f, 0.f, 0.f);
    if (row0 + r < N) v = *(const float4*)&In[(size_t)(row0 + r) * HDIM + c4];
    half4v hh, ll;
    hh.x = (_Float16)v.x; ll.x = (_Float16)(v.x - (float)hh.x);
    hh.y = (_Float16)v.y; ll.y = (_Float16)(v.y - (float)hh.y);
    hh.z = (_Float16)v.z; ll.z = (_Float16)(v.z - (float)hh.z);
    hh.w = (_Float16)v.w; ll.w = (_Float16)(v.w - (float)hh.w);
    *(half4v*)&Ab[0][r * PA + c4] = hh;
    *(half4v*)&Ab[1][r * PA + c4] = ll;
  }

  _Float16 *Hh, *Hl;
  if constexpr (NH == 2) { Hh = Hb[0]; Hl = Hb[1]; }
  else { Hh = Ab[0]; Hl = Ab[1]; }

  f32x4 acc2[MF][4];
#pragma unroll
  for (int f = 0; f < 4; ++f) {
    float bv = b2[wc * 64 + f * 16 + l15];
#pragma unroll
    for (int m = 0; m < MF; ++m) acc2[m][f] = (f32x4){bv, bv, bv, bv};
  }

  for (int h = 0; h < NH; ++h) {
    f32x4 acc1[MF][4];
#pragma unroll
    for (int f = 0; f < 4; ++f) {
      float bv = b1[h * 128 + wc * 64 + f * 16 + l15];
#pragma unroll
      for (int m = 0; m < MF; ++m) acc1[m][f] = (f32x4){bv, bv, bv, bv};
    }
#pragma unroll
    for (int slab = 0; slab < 2; ++slab) {
      __syncthreads();
      stage_w_slab(Wb[0], Wb[1], w1hi + (size_t)h * 128 * 128, w1lo + (size_t)h * 128 * 128,
                   128, slab * 64);
      __syncthreads();
      gemm_slab<MF>(Ab[0], Ab[1], Wb[0], Wb[1], rowbase, l15, l4, wc, slab, acc1);
    }
    __syncthreads();
#pragma unroll
    for (int m = 0; m < MF; ++m)
#pragma unroll
      for (int f = 0; f < 4; ++f)
#pragma unroll
        for (int r = 0; r < 4; ++r) {
          float v = fmaxf(acc1[m][f][r], 0.f);
          _Float16 hh = (_Float16)v;
          int row = rowbase + m * 16 + l4 * 4 + r;
          int ck = wc * 64 + f * 16 + l15;
          Hh[row * PA + ck] = hh;
          Hl[row * PA + ck] = (_Float16)(v - (float)hh);
        }
#pragma unroll
    for (int slab = 0; slab < 2; ++slab) {
      __syncthreads();
      stage_w_slab(Wb[0], Wb[1], w2hi, w2lo, NH * 128, h * 128 + slab * 64);
      __syncthreads();
      gemm_slab<MF>(Hh, Hl, Wb[0], Wb[1], rowbase, l15, l4, wc, slab, acc2);
    }
  }

  __syncthreads();
  float* psum = (float*)&Wb[0][0];
  float* psq = psum + 256;
#pragma unroll
  for (int f = 0; f < 4; ++f) {
    float s = 0.f, q = 0.f;
#pragma unroll
    for (int m = 0; m < MF; ++m)
#pragma unroll
      for (int r = 0; r < 4; ++r) {
        int grow = row0 + rowbase + m * 16 + l4 * 4 + r;
        float v = acc2[m][f][r];
        if (grow < N) {
          Out[(size_t)grow * HDIM + wc * 64 + f * 16 + l15] = (_Float16)v;
          s += v;
          q += v * v;
        }
      }
    s += __shfl_xor(s, 16); q += __shfl_xor(q, 16);
    s += __shfl_xor(s, 32); q += __shfl_xor(q, 32);
    if (l4 == 0) {
      psum[wr * 128 + wc * 64 + f * 16 + l15] = s;
      psq[wr * 128 + wc * 64 + f * 16 + l15] = q;
    }
  }
  __syncthreads();
  if (tid < 128) {
    atomicAdd(&stats[tid], psum[tid] + psum[128 + tid]);
    atomicAdd(&stats[128 + tid], psq[tid] + psq[128 + tid]);
  }
}

// ============================ BN apply (+identity / +dual BN), f16 io ============
template <int DUAL>
__global__ __launch_bounds__(256) void bnrelu_kernel(
    const _Float16* __restrict__ h1, const float* __restrict__ s1,
    const float* __restrict__ g1, const float* __restrict__ bt1,
    const _Float16* __restrict__ h2, const float* __restrict__ s2,
    const float* __restrict__ g2, const float* __restrict__ bt2,
    _Float16* __restrict__ out, float invN, int nv8) {
  int tid = blockIdx.x * 256 + threadIdx.x;
  int c8 = (tid & 15) * 8;
  float a1[8], r1[8], a2[8], r2[8];
#pragma unroll
  for (int j = 0; j < 8; ++j) {
    int c = c8 + j;
    float m = s1[c] * invN;
    float v = fmaxf(s1[128 + c] * invN - m * m, 0.f);
    a1[j] = g1[c] * rsqrtf(v + BN_EPS_F);
    r1[j] = bt1[c] - m * a1[j];
    if constexpr (DUAL) {
      float m2 = s2[c] * invN;
      float v2 = fmaxf(s2[128 + c] * invN - m2 * m2, 0.f);
      a2[j] = g2[c] * rsqrtf(v2 + BN_EPS_F);
      r2[j] = bt2[c] - m2 * a2[j];
    } else {
      a2[j] = 0.f; r2[j] = 0.f;
    }
  }
  int stride = gridDim.x * 256;
  for (int i = tid; i < nv8; i += stride) {
    half8 u = ((const half8*)h1)[i];
    half8 v = ((const half8*)h2)[i];
    half8 o;
#pragma unroll
    for (int j = 0; j < 8; ++j) {
      float y = fmaxf(fmaf((float)u[j], a1[j], r1[j]), 0.f);
      if constexpr (DUAL) y += fmaxf(fmaf((float)v[j], a2[j], r2[j]), 0.f);
      else y += (float)v[j];
      o[j] = (_Float16)y;
    }
    ((half8*)out)[i] = o;
  }
}

// ============================ Tail (reads f32 agg, GIN 128->32->3) ============================
__global__ __launch_bounds__(256, 1) void tail_kernel(
    const float* __restrict__ A, const float* __restrict__ W1, const float* __restrict__ b1,
    const float* __restrict__ W2, const float* __restrict__ b2, float* __restrict__ out, int N) {
  __shared__ float Xs[64][132];
  __shared__ float W1s[128][32];
  __shared__ float H1s[64][36];
  __shared__ float W2s[96];
  __shared__ float b1s[32];
  __shared__ float b2s[3];
  int tid = threadIdx.x;
  int row0 = blockIdx.x * 64;
#pragma unroll
  for (int it = 0; it < 8; ++it) {
    int l = tid + it * 256, r = l >> 5, c4 = l & 31;
    float4 v = make_float4(0.f, 0.f, 0.f, 0.f);
    if (row0 + r < N) v = *(const float4*)&A[(size_t)(row0 + r) * HDIM + c4 * 4];
    *(float4*)&Xs[r][c4 * 4] = v;
  }
#pragma unroll
  for (int it = 0; it < 4; ++it) {
    int l = tid + it * 256;
    int r = l >> 3, c4 = l & 7;
    *(float4*)&W1s[r][c4 * 4] = *(const float4*)&W1[r * 32 + c4 * 4];
  }
  if (tid < 96) W2s[tid] = W2[tid];
  if (tid < 32) b1s[tid] = b1[tid];
  if (tid < 3) b2s[tid] = b2[tid];
  __syncthreads();
  {
    int r = tid >> 2;
    int c0 = (tid & 3) * 8;
    float acc1[8];
#pragma unroll
    for (int j = 0; j < 8; ++j) acc1[j] = b1s[c0 + j];
#pragma unroll 2
    for (int k = 0; k < 128; ++k) {
      float xv = Xs[r][k];
      float4 wA = *(const float4*)&W1s[k][c0];
      float4 wB = *(const float4*)&W1s[k][c0 + 4];
      acc1[0] = fmaf(xv, wA.x, acc1[0]);
      acc1[1] = fmaf(xv, wA.y, acc1[1]);
      acc1[2] = fmaf(xv, wA.z, acc1[2]);
      acc1[3] = fmaf(xv, wA.w, acc1[3]);
      acc1[4] = fmaf(xv, wB.x, acc1[4]);
      acc1[5] = fmaf(xv, wB.y, acc1[5]);
      acc1[6] = fmaf(xv, wB.z, acc1[6]);
      acc1[7] = fmaf(xv, wB.w, acc1[7]);
    }
#pragma unroll
    for (int j = 0; j < 8; ++j) H1s[r][c0 + j] = fmaxf(acc1[j], 0.f);
  }
  __syncthreads();
  if (tid < 192) {
    int r = tid / 3, c = tid - (tid / 3) * 3;
    float accv = b2s[c];
#pragma unroll
    for (int k = 0; k < 32; ++k) accv = fmaf(H1s[r][k], W2s[k * 3 + c], accv);
    if (row0 + r < N) out[(size_t)(row0 + r) * 3 + c] = accv;
  }
}

// ============================ Host launcher ============================
extern "C" void kernel_launch(void* const* d_in, const int* in_sizes, int n_in,
                              void* d_out, int out_size, void* d_ws, size_t ws_size,
                              hipStream_t stream) {
  const float* x = (const float*)d_in[0];
  const int* ei = (const int*)d_in[1];
  const float* head_w1 = (const float*)d_in[2];
  const float* head_b1 = (const float*)d_in[3];
  const float* head_w2 = (const float*)d_in[4];
  const float* head_b2 = (const float*)d_in[5];
  const float* head_g = (const float*)d_in[6];
  const float* head_bt = (const float*)d_in[7];
  const float* res_w1 = (const float*)d_in[8];
  const float* res_b1 = (const float*)d_in[9];
  const float* res_w2 = (const float*)d_in[10];
  const float* res_b2 = (const float*)d_in[11];
  const float* res_g = (const float*)d_in[12];
  const float* res_bt = (const float*)d_in[13];
  const float* tail_w1 = (const float*)d_in[14];
  const float* tail_b1 = (const float*)d_in[15];
  const float* tail_w2 = (const float*)d_in[16];
  const float* tail_b2 = (const float*)d_in[17];

  const int N = in_sizes[0] / HDIM;
  const int E = in_sizes[1] / 2;
  const int NC = (N + 255) >> CSH;  // coarse regions (<= CMAX)
  const int* srcp = ei;
  const int* dstp = ei + E;

  char* base = (char*)d_ws;
  size_t off = 0;
  auto alloc = [&](size_t bytes) -> void* {
    void* p = base + off;
    off += (bytes + 255) & ~(size_t)255;
    return p;
  };
  _Float16* F0 = (_Float16*)alloc((size_t)N * HDIM * 2);
  _Float16* F1 = (_Float16*)alloc((size_t)N * HDIM * 2);
  _Float16* F2 = (_Float16*)alloc((size_t)N * HDIM * 2);
  _Float16* F3 = (_Float16*)alloc((size_t)N * HDIM * 2);
  float* A = (float*)alloc((size_t)N * HDIM * 4);
  int* colb = (int*)alloc((size_t)E * 4);
  int* rowptr = (int*)alloc((size_t)(N + 1) * 4);
  int* gcnt = (int*)alloc((size_t)CMAX * 4);
  int* gbase = (int*)alloc((size_t)(CMAX + 1) * 4);
  int* gcur = (int*)alloc((size_t)CMAX * 4);
  float* S = (float*)alloc(8 * 256 * 4);
  _Float16* whi = (_Float16*)alloc(262144 * 2);
  _Float16* wlo = (_Float16*)alloc(262144 * 2);
  // aliases (disjoint lifetimes): binned (E u32, CSR build only) lives in A's slot
  // (A first written after region_build). X16 (f16 x) in F3 (first real write at yB1).
  unsigned int* binned = (unsigned int*)A;
  _Float16* X16 = F3;
  (void)ws_size; (void)n_in; (void)out_size;

  const float invN = 1.0f / (float)N;
  const int aggGrid = (N + 3) / 4;
  const int gridH = (N + 31) / 32, gridR = (N + 63) / 64;
  const int nv8 = N * (HDIM / 8);

  // ---- prep ----
  wprep_all<<<1024, 256, 0, stream>>>(head_w1, head_w2, res_w1, res_w2, whi, wlo);
  xcvt_kernel<<<2048, 256, 0, stream>>>(x, X16, N * (HDIM / 4));
  hipMemsetAsync(gcnt, 0, (size_t)CMAX * 4, stream);
  hipMemsetAsync(S, 0, 8 * 256 * 4, stream);
  coarse_hist<<<512, 256, 0, stream>>>(dstp, E, gcnt);
  coarse_scan<<<1, 256, 0, stream>>>(gcnt, gbase, gcur, E);
  bin_chunk<<<(E + CHUNK - 1) / CHUNK, 256, 0, stream>>>(srcp, dstp, E, gcur, binned);
  region_build<<<NC, 256, 0, stream>>>(binned, gbase, rowptr, colb, N, E);

  const _Float16* u1h[6]; const _Float16* u1l[6];
  const _Float16* u2h[6]; const _Float16* u2l[6];
  for (int u = 0; u < 6; ++u) {
    u1h[u] = whi + 65536 + u * 32768; u1l[u] = wlo + 65536 + u * 32768;
    u2h[u] = whi + 65536 + u * 32768 + 16384; u2l[u] = wlo + 65536 + u * 32768 + 16384;
  }

  // ---- head: agg(x16) -> A ; MLP -> F0 (h_head), statsH(S) ----
  agg_f16_kernel<0><<<aggGrid, 256, 0, stream>>>(X16, A, rowptr, colb,
      nullptr, nullptr, nullptr, invN, N);
  mlp_kernel<1, 2><<<gridH, 256, 0, stream>>>(A, F0, whi, wlo, head_b1,
      whi + 32768, wlo + 32768, head_b2, S, N);
  // ---- u0: aggBN(F0; statsH) -> A ; MLP -> F1 (h0), stats0 ----
  agg_f16_kernel<1><<<aggGrid, 256, 0, stream>>>(F0, A, rowptr, colb,
      S, head_g, head_bt, invN, N);
  mlp_kernel<2, 1><<<gridR, 256, 0, stream>>>(A, F1, u1h[0], u1l[0], res_b1,
      u2h[0], u2l[0], res_b2, S + 256, N);
  // ---- u1: aggBN(F1; stats0) -> A ; MLP -> F2 (h1), stats1 ----
  agg_f16_kernel<1><<<aggGrid, 256, 0, stream>>>(F1, A, rowptr, colb,
      S + 256, res_g, res_bt, invN, N);
  mlp_kernel<2, 1><<<gridR, 256, 0, stream>>>(A, F2, u1h[1], u1l[1], res_b1 + HDIM,
      u2h[1], u2l[1], res_b2 + HDIM, S + 512, N);
  // ---- yB1 = relu(bn1(h1)) + relu(bnH(h_head)) -> F3 ----
  bnrelu_kernel<1><<<2048, 256, 0, stream>>>(F2, S + 512, res_g + HDIM, res_bt + HDIM,
      F0, S, head_g, head_bt, F3, invN, nv8);
  // ---- u2: agg(F3) -> A ; MLP -> F0 (h2), stats2 ----
  agg_f16_kernel<0><<<aggGrid, 256, 0, stream>>>(F3, A, rowptr, colb,
      nullptr, nullptr, nullptr, invN, N);
  mlp_kernel<2, 1><<<gridR, 256, 0, stream>>>(A, F0, u1h[2], u1l[2], res_b1 + 2 * HDIM,
      u2h[2], u2l[2], res_b2 + 2 * HDIM, S + 768, N);
  // ---- u3: aggBN(F0; stats2) -> A ; MLP -> F1 (h3), stats3 ----
  agg_f16_kernel<1><<<aggGrid, 256, 0, stream>>>(F0, A, rowptr, colb,
      S + 768, res_g + 2 * HDIM, res_bt + 2 * HDIM, invN, N);
  mlp_kernel<2, 1><<<gridR, 256, 0, stream>>>(A, F1, u1h[3], u1l[3], res_b1 + 3 * HDIM,
      u2h[3], u2l[3], res_b2 + 3 * HDIM, S + 1024, N);
  // ---- yB2 = relu(bn3(h3)) + yB1 -> F2 ----
  bnrelu_kernel<0><<<2048, 256, 0, stream>>>(F1, S + 1024, res_g + 3 * HDIM,
      res_bt + 3 * HDIM, F3, nullptr, nullptr, nullptr, F2, invN, nv8);
  // ---- u4: agg(F2) -> A ; MLP -> F0 (h4), stats4 ----
  agg_f16_kernel<0><<<aggGrid, 256, 0, stream>>>(F2, A, rowptr, colb,
      nullptr, nullptr, nullptr, invN, N);
  mlp_kernel<2, 1><<<gridR, 256, 0, stream>>>(A, F0, u1h[4], u1l[4], res_b1 + 4 * HDIM,
      u2h[4], u2l[4], res_b2 + 4 * HDIM, S + 1280, N);
  // ---- u5: aggBN(F0; stats4) -> A ; MLP -> F1 (h5), stats5 ----
  agg_f16_kernel<1><<<aggGrid, 256, 0, stream>>>(F0, A, rowptr, colb,
      S + 1280, res_g + 4 * HDIM, res_bt + 4 * HDIM, invN, N);
  mlp_kernel<2, 1><<<gridR, 256, 0, stream>>>(A, F1, u1h[5], u1l[5], res_b1 + 5 * HDIM,
      u2h[5], u2l[5], res_b2 + 5 * HDIM, S + 1536, N);
  // ---- yB3 = relu(bn5(h5)) + yB2 -> F3 ----
  bnrelu_kernel<0><<<2048, 256, 0, stream>>>(F1, S + 1536, res_g + 5 * HDIM,
      res_bt + 5 * HDIM, F2, nullptr, nullptr, nullptr, F3, invN, nv8);
  // ---- tail: agg(F3) -> A ; GIN(128->32->3) -> out ----
  agg_f16_kernel<0><<<aggGrid, 256, 0, stream>>>(F3, A, rowptr, colb,
      nullptr, nullptr, nullptr, invN, N);
  tail_kernel<<<gridR, 256, 0, stream>>>(A, tail_w1, tail_b1, tail_w2, tail_b2,
                                         (float*)d_out, N);
}